// Round 6
// baseline (237.606 us; speedup 1.0000x reference)
//
#include <hip/hip_runtime.h>

// Batched 16x16 Sinkhorn (VotingLayer) via scaling vectors.
// S_t = diag(r)*S0*diag(c), S0 = v^T + 1e-6;  c = 1/(S0^T r), r = 1/(S0 c).
// 16 lanes handle TWO matrices (A,B packed in v2f lanes .x/.y) so every
// v_pk_fma_f32 advances both matrices' dependency chains at once (2x ILP at
// same chain depth — fix for the latency-bound round-3 kernel).
//
// Lane idx (0..15): r = idx&3, c = idx>>2; lane owns 4x4 block
//   bp[i][j] = (S0_A[4r+i][4c+j], S0_B[4r+i][4c+j]).
// Column allreduce: quad_perm DPP over lanes {4c..4c+3} (xor bits 0-1).
// Row allreduce: row_ror:4/8 DPP over lanes {r,r+4,r+8,r+12} (within the
// aligned 16-lane group). Matrix is never updated; final rescale at the end.

#define NITER 10
typedef float v2f __attribute__((ext_vector_type(2)));

template <int CTRL>
__device__ __forceinline__ float dpp_add(float x) {
    int xi = __builtin_bit_cast(int, x);
    int yi = __builtin_amdgcn_update_dpp(xi, xi, CTRL, 0xF, 0xF, false);
    return x + __builtin_bit_cast(float, yi);
}

__device__ __forceinline__ v2f quad_allreduce(v2f a) {   // lanes xor 1,2
    a.x = dpp_add<0x4E>(dpp_add<0xB1>(a.x));
    a.y = dpp_add<0x4E>(dpp_add<0xB1>(a.y));
    return a;
}
__device__ __forceinline__ v2f row_allreduce(v2f a) {    // lanes +4,+8 (ror)
    a.x = dpp_add<0x128>(dpp_add<0x124>(a.x));
    a.y = dpp_add<0x128>(dpp_add<0x124>(a.y));
    return a;
}
__device__ __forceinline__ v2f rcp2(v2f a) {
    return (v2f){__builtin_amdgcn_rcpf(a.x), __builtin_amdgcn_rcpf(a.y)};
}

__global__ __launch_bounds__(256) void sinkhorn16_kernel(
        const float* __restrict__ v, float* __restrict__ out, int npair) {
    const int tid  = blockIdx.x * 256 + threadIdx.x;
    const int pair = tid >> 4;
    if (pair >= npair) return;
    const int idx = tid & 15;
    const int r   = idx & 3;
    const int c   = idx >> 2;

    const float* baseA = v + (size_t)pair * 512 + c * 64 + r * 4;

    // bp[i][j] = (S0_A[4r+i][4c+j], S0_B[4r+i][4c+j])
    v2f bp[4][4];
#pragma unroll
    for (int j = 0; j < 4; ++j) {
        const float4 fa = *(const float4*)(baseA + 16 * j);        // matrix A
        const float4 fb = *(const float4*)(baseA + 256 + 16 * j);  // matrix B
        bp[0][j] = (v2f){fa.x + 1e-6f, fb.x + 1e-6f};
        bp[1][j] = (v2f){fa.y + 1e-6f, fb.y + 1e-6f};
        bp[2][j] = (v2f){fa.z + 1e-6f, fb.z + 1e-6f};
        bp[3][j] = (v2f){fa.w + 1e-6f, fb.w + 1e-6f};
    }

    v2f rv[4], cj[4];
#pragma unroll
    for (int i = 0; i < 4; ++i) rv[i] = (v2f){1.0f, 1.0f};

#pragma unroll
    for (int it = 0; it < NITER; ++it) {
        // ---- column phase: c_j = 1/sum_i S0[i][j]*r_i ----
#pragma unroll
        for (int j = 0; j < 4; ++j) {
            v2f acc = bp[0][j] * rv[0];
            acc += bp[1][j] * rv[1];
            acc += bp[2][j] * rv[2];
            acc += bp[3][j] * rv[3];
            cj[j] = rcp2(quad_allreduce(acc));
        }
        // ---- row phase: r_i = 1/sum_j S0[i][j]*c_j ----
#pragma unroll
        for (int i = 0; i < 4; ++i) {
            v2f t = bp[i][0] * cj[0];
            t += bp[i][1] * cj[1];
            t += bp[i][2] * cj[2];
            t += bp[i][3] * cj[3];
            rv[i] = rcp2(row_allreduce(t));
        }
    }

    // ---- epilogue: out[4r+i][4c+j] = bp[i][j] * r_i * c_j ----
    float* obA = out + (size_t)pair * 512 + r * 64 + c * 4;
#pragma unroll
    for (int i = 0; i < 4; ++i) {
        const v2f s0 = bp[i][0] * cj[0] * rv[i];
        const v2f s1 = bp[i][1] * cj[1] * rv[i];
        const v2f s2 = bp[i][2] * cj[2] * rv[i];
        const v2f s3 = bp[i][3] * cj[3] * rv[i];
        *(float4*)(obA + 16 * i)       = make_float4(s0.x, s1.x, s2.x, s3.x);
        *(float4*)(obA + 256 + 16 * i) = make_float4(s0.y, s1.y, s2.y, s3.y);
    }
}

extern "C" void kernel_launch(void* const* d_in, const int* in_sizes, int n_in,
                              void* d_out, int out_size, void* d_ws, size_t ws_size,
                              hipStream_t stream) {
    const float* v = (const float*)d_in[0];
    float* out = (float*)d_out;
    const int nmat  = in_sizes[0] >> 8;           // 131072
    const int npair = nmat >> 1;                  // 65536 (nmat is even)
    const int total_threads = npair * 16;         // 1,048,576
    const int block = 256;
    const int grid = (total_threads + block - 1) / block;  // 4096
    sinkhorn16_kernel<<<grid, block, 0, stream>>>(v, out, npair);
}